// Round 6
// baseline (94.653 us; speedup 1.0000x reference)
//
#include <hip/hip_runtime.h>
#include <cstdint>

typedef unsigned int u32;
typedef unsigned short u16;
typedef unsigned long long u64;
typedef __attribute__((ext_vector_type(4))) float f32x4;
typedef __attribute__((ext_vector_type(8))) short s16x8;

#define D_IN   784
#define D_H    2048
#define D_O    10
#define T_STEPS 100
#define KB1    25          // ceil(784/32) k-blocks for layer-1 GEMM

static __device__ __forceinline__ u16 f2bf_rn(float f) {
  u32 u = __float_as_uint(f);
  u32 r = u + 0x7FFFu + ((u >> 16) & 1u);
  return (u16)(r >> 16);
}
static __device__ __forceinline__ float bf2f(u16 h) {
  return __uint_as_float(((u32)h) << 16);
}

// ---------------------------------------------------------------------------
// K0: merged prep. Blocks 0..199: x triple-split; 200..999: W1 triple-split
// (LDS-staged coalesced loads); 1000..1015: W2 hi/lo B-fragments.
// ---------------------------------------------------------------------------
__global__ __launch_bounds__(256) void k_prep(const float* __restrict__ x,
                                              const float* __restrict__ W1,
                                              const float* __restrict__ W2,
                                              uint4* __restrict__ Xs,
                                              uint4* __restrict__ Ws,
                                              u32* __restrict__ Phi,
                                              u32* __restrict__ Plo) {
  const int blk = blockIdx.x, tid = threadIdx.x;
  if (blk >= 1000) {
    int t = (blk - 1000) * 256 + tid;
    if (t >= 64 * 64) return;
    int kb = t >> 6, l = t & 63;
    int o = l & 15;
    int kbase = kb * 32 + ((l >> 4) << 3);
    u32 hw[4], lw[4];
#pragma unroll
    for (int p = 0; p < 4; ++p) {
      u32 hp = 0, lp = 0;
#pragma unroll
      for (int q = 0; q < 2; ++q) {
        float f = (o < D_O) ? W2[o * D_H + kbase + 2 * p + q] : 0.0f;
        u16 h = f2bf_rn(f);
        float rr = __fsub_rn(f, bf2f(h));
        u16 lo = f2bf_rn(rr);
        hp |= ((u32)h) << (16 * q);
        lp |= ((u32)lo) << (16 * q);
      }
      hw[p] = hp; lw[p] = lp;
    }
    int base = (kb * 64 + l) * 4;
#pragma unroll
    for (int p = 0; p < 4; ++p) { Phi[base + p] = hw[p]; Plo[base + p] = lw[p]; }
    return;
  }
  __shared__ float sa[64][36];
  const float* src; uint4* dst; int rb, kb, nfr;
  if (blk < 200) { src = x;  dst = Xs; rb = blk / 25;        kb = blk % 25;        nfr = 32; }
  else           { src = W1; dst = Ws; rb = (blk - 200) / 25; kb = (blk - 200) % 25; nfr = 128; }
  {
    int r = tid >> 2, q = tid & 3;
    int row = rb * 64 + r;
    int kg = kb * 32 + q * 8;
    const float* rp = src + (size_t)row * D_IN + kg;
    float4 z = make_float4(0.f, 0.f, 0.f, 0.f);
    float4 v0 = (kg + 3 < D_IN) ? *(const float4*)rp : z;
    float4 v1 = (kg + 7 < D_IN) ? *(const float4*)(rp + 4) : z;
    *(float4*)&sa[r][q * 8]     = v0;
    *(float4*)&sa[r][q * 8 + 4] = v1;
  }
  __syncthreads();
  const int fr = tid >> 6, l = tid & 63;
  const int row_l = fr * 16 + (l & 15), kl = (l >> 4) * 8;
  u32 w0[4], w1[4], w2[4];
#pragma unroll
  for (int p = 0; p < 4; ++p) {
    u32 a0 = 0, a1 = 0, a2 = 0;
#pragma unroll
    for (int q = 0; q < 2; ++q) {
      float v = sa[row_l][kl + 2 * p + q];
      u16 s0 = f2bf_rn(v); float r1 = __fsub_rn(v, bf2f(s0));
      u16 s1 = f2bf_rn(r1); float r2 = __fsub_rn(r1, bf2f(s1));
      u16 s2 = f2bf_rn(r2);
      a0 |= ((u32)s0) << (16 * q);
      a1 |= ((u32)s1) << (16 * q);
      a2 |= ((u32)s2) << (16 * q);
    }
    w0[p] = a0; w1[p] = a1; w2[p] = a2;
  }
  size_t bi = ((size_t)kb * nfr + rb * 4 + fr) * 64 + l;
  size_t ss = (size_t)KB1 * nfr * 64;
  dst[0 * ss + bi] = make_uint4(w0[0], w0[1], w0[2], w0[3]);
  dst[1 * ss + bi] = make_uint4(w1[0], w1[1], w1[2], w1[3]);
  dst[2 * ss + bi] = make_uint4(w2[0], w2[1], w2[2], w2[3]);
}

// ---------------------------------------------------------------------------
// K1: cur1 = x @ W1^T + b1 via 6-product bf16-triple MFMA, XCD-swizzled grid.
// ---------------------------------------------------------------------------
__global__ __launch_bounds__(512) void k_gemm1(const uint4* __restrict__ Xs,
                                               const uint4* __restrict__ Ws,
                                               const float* __restrict__ b1,
                                               float* __restrict__ cur1) {
  __shared__ float4 comb[16][64];   // 16 KB
  const int tid = threadIdx.x, wave = tid >> 6, lane = tid & 63;
  const int id = blockIdx.x;
  const int nb = (id & 7) * 4 + ((id >> 3) & 3);   // 0..31
  const int mb = id >> 5;                          // 0..7
  const int wn = wave & 3;
  const int nfrag = nb * 4 + wn;
  const size_t ssx = (size_t)KB1 * 32 * 64;
  const size_t ssw = (size_t)KB1 * 128 * 64;
  f32x4 acc[4] = {{0.f,0.f,0.f,0.f},{0.f,0.f,0.f,0.f},{0.f,0.f,0.f,0.f},{0.f,0.f,0.f,0.f}};
  for (int kb = (wave >> 2); kb < KB1; kb += 2) {
    const size_t bb = (size_t)kb * 8192 + (size_t)nfrag * 64 + lane;
    uint4 b0u = Ws[0 * ssw + bb];
    uint4 b1u = Ws[1 * ssw + bb];
    uint4 b2u = Ws[2 * ssw + bb];
    s16x8 B0 = __builtin_bit_cast(s16x8, b0u);
    s16x8 B1 = __builtin_bit_cast(s16x8, b1u);
    s16x8 B2 = __builtin_bit_cast(s16x8, b2u);
#pragma unroll
    for (int fm = 0; fm < 4; ++fm) {
      const size_t ab = (size_t)kb * 2048 + (size_t)(mb * 4 + fm) * 64 + lane;
      uint4 a0u = Xs[0 * ssx + ab];
      uint4 a1u = Xs[1 * ssx + ab];
      uint4 a2u = Xs[2 * ssx + ab];
      s16x8 A0 = __builtin_bit_cast(s16x8, a0u);
      s16x8 A1 = __builtin_bit_cast(s16x8, a1u);
      s16x8 A2 = __builtin_bit_cast(s16x8, a2u);
      acc[fm] = __builtin_amdgcn_mfma_f32_16x16x32_bf16(A0, B0, acc[fm], 0, 0, 0);
      acc[fm] = __builtin_amdgcn_mfma_f32_16x16x32_bf16(A0, B1, acc[fm], 0, 0, 0);
      acc[fm] = __builtin_amdgcn_mfma_f32_16x16x32_bf16(A1, B0, acc[fm], 0, 0, 0);
      acc[fm] = __builtin_amdgcn_mfma_f32_16x16x32_bf16(A1, B1, acc[fm], 0, 0, 0);
      acc[fm] = __builtin_amdgcn_mfma_f32_16x16x32_bf16(A0, B2, acc[fm], 0, 0, 0);
      acc[fm] = __builtin_amdgcn_mfma_f32_16x16x32_bf16(A2, B0, acc[fm], 0, 0, 0);
    }
  }
  if (wave >= 4) {
#pragma unroll
    for (int fm = 0; fm < 4; ++fm)
      comb[wn * 4 + fm][lane] = make_float4(acc[fm][0], acc[fm][1], acc[fm][2], acc[fm][3]);
  }
  __syncthreads();
  if (wave < 4) {
    const float bv = b1[nfrag * 16 + (lane & 15)];
    const int rbase = (lane >> 4) * 4, col = lane & 15;
#pragma unroll
    for (int fm = 0; fm < 4; ++fm) {
      float4 o = comb[wn * 4 + fm][lane];
      float v[4] = {acc[fm][0] + o.x, acc[fm][1] + o.y, acc[fm][2] + o.z, acc[fm][3] + o.w};
#pragma unroll
      for (int r = 0; r < 4; ++r) {
        int m = mb * 64 + fm * 16 + rbase + r;
        cur1[(size_t)m * D_H + nfrag * 16 + col] = v[r] + bv;
      }
    }
  }
}

// ---------------------------------------------------------------------------
// K2a: layer-1 recurrence only -> global bit-matrix bits[b][h32][112-step].
// No LDS, no barriers. Lane t of the wave captures step-t's ballot via
// v_cndmask select (alo = lane==t ? msk : alo); dumped as coalesced stores.
// ---------------------------------------------------------------------------
__global__ __launch_bounds__(512) void k2a(const float* __restrict__ cur1,
                                           const float* __restrict__ beta1p,
                                           u32* __restrict__ bits) {
  const int b = blockIdx.x, tid = threadIdx.x;
  const int wave = tid >> 6, lane = tid & 63;
  const float b1c = fminf(fmaxf(beta1p[0], 0.0f), 1.0f);
  float cv[4], memv[4]; bool sp[4];
  u32 alo[4], ahi[4];
#pragma unroll
  for (int j = 0; j < 4; ++j) {
    cv[j] = cur1[(size_t)b * D_H + j * 512 + tid];
    memv[j] = 0.0f; sp[j] = false; alo[j] = 0u; ahi[j] = 0u;
  }
  for (int t = 0; t < 64; ++t) {
    const bool mine = (lane == t);
#pragma unroll
    for (int j = 0; j < 4; ++j) {
      float m = __fmul_rn(b1c, memv[j]);
      m = __fadd_rn(m, cv[j]);
      if (sp[j]) m = __fsub_rn(m, 1.0f);
      sp[j] = (m > 1.0f);
      memv[j] = m;
      u64 msk = __ballot(sp[j]);
      alo[j] = mine ? (u32)msk : alo[j];
      ahi[j] = mine ? (u32)(msk >> 32) : ahi[j];
    }
  }
#pragma unroll
  for (int j = 0; j < 4; ++j) {
    size_t r0 = ((size_t)b * 64 + j * 16 + wave * 2) * 112;
    bits[r0 + lane]       = alo[j];
    bits[r0 + 112 + lane] = ahi[j];
    alo[j] = 0u; ahi[j] = 0u;
  }
  for (int t = 64; t < T_STEPS; ++t) {
    const bool mine = (lane == t - 64);
#pragma unroll
    for (int j = 0; j < 4; ++j) {
      float m = __fmul_rn(b1c, memv[j]);
      m = __fadd_rn(m, cv[j]);
      if (sp[j]) m = __fsub_rn(m, 1.0f);
      sp[j] = (m > 1.0f);
      memv[j] = m;
      u64 msk = __ballot(sp[j]);
      alo[j] = mine ? (u32)msk : alo[j];
      ahi[j] = mine ? (u32)(msk >> 32) : ahi[j];
    }
  }
  if (lane < 48) {   // t = 64..111; lanes 36..47 hold zeros (pad rows)
#pragma unroll
    for (int j = 0; j < 4; ++j) {
      size_t r0 = ((size_t)b * 64 + j * 16 + wave * 2) * 112 + 64;
      bits[r0 + lane]       = alo[j];
      bits[r0 + 112 + lane] = ahi[j];
    }
  }
}

// ---------------------------------------------------------------------------
// K2bc: cur2 MFMA (waves 0..6, Phi/Plo LDS-staged in 8-kb chunks, cheap
// 15-op bit->bf16 expand) + layer-2 recurrence + softmax.
// ---------------------------------------------------------------------------
__global__ __launch_bounds__(512) void k2bc(const u32* __restrict__ bits,
                                            const u32* __restrict__ Phi,
                                            const u32* __restrict__ Plo,
                                            const float* __restrict__ b2,
                                            const float* __restrict__ beta2p,
                                            float* __restrict__ out) {
  __shared__ uint4 PhiS[8][64];
  __shared__ uint4 PloS[8][64];
  __shared__ float c2[112][18];
  const int b = blockIdx.x, tid = threadIdx.x;
  const int wave = tid >> 6, lane = tid & 63;
  const float b2c = fminf(fmaxf(beta2p[0], 0.0f), 1.0f);
  f32x4 acc = {0.f, 0.f, 0.f, 0.f};
  const int trow = wave * 16 + (lane & 15);
  const int shift = (lane >> 4) * 8;
  const u32* brow = bits + (size_t)b * 64 * 112;
  for (int c = 0; c < 8; ++c) {
    __syncthreads();
    PhiS[wave][lane] = *(const uint4*)(Phi + (size_t)((c * 8 + wave) * 64 + lane) * 4);
    PloS[wave][lane] = *(const uint4*)(Plo + (size_t)((c * 8 + wave) * 64 + lane) * 4);
    __syncthreads();
    if (wave < 7) {
#pragma unroll
      for (int kk = 0; kk < 8; ++kk) {
        const int kb = c * 8 + kk;
        u32 w8 = (brow[kb * 112 + trow] >> shift) & 0xFFu;
        u32 u = w8 | (w8 << 15);
        uint4 a0u;
        ((u32*)&a0u)[0] = ( u        & 0x00010001u) * 0x3F80u;
        ((u32*)&a0u)[1] = ((u >> 2)  & 0x00010001u) * 0x3F80u;
        ((u32*)&a0u)[2] = ((u >> 4)  & 0x00010001u) * 0x3F80u;
        ((u32*)&a0u)[3] = ((u >> 6)  & 0x00010001u) * 0x3F80u;
        s16x8 a   = __builtin_bit_cast(s16x8, a0u);
        s16x8 bhi = __builtin_bit_cast(s16x8, PhiS[kk][lane]);
        s16x8 blo = __builtin_bit_cast(s16x8, PloS[kk][lane]);
        acc = __builtin_amdgcn_mfma_f32_16x16x32_bf16(a, bhi, acc, 0, 0, 0);
        acc = __builtin_amdgcn_mfma_f32_16x16x32_bf16(a, blo, acc, 0, 0, 0);
      }
    }
  }
  if (wave < 7) {
    const int colw = lane & 15, rbase = (lane >> 4) * 4;
#pragma unroll
    for (int r = 0; r < 4; ++r) c2[wave * 16 + rbase + r][colw] = acc[r];
  }
  __syncthreads();
  if (tid < 16) {
    const int o = tid;
    const bool valid = (o < D_O);
    const float bb = valid ? b2[o] : 0.0f;
    float m2 = 0.0f; bool s2 = false; int cnt = 0;
    for (int t0 = 0; t0 < T_STEPS; t0 += 10) {
      float cc[10];
#pragma unroll
      for (int i = 0; i < 10; ++i) cc[i] = c2[t0 + i][o];
#pragma unroll
      for (int i = 0; i < 10; ++i) {
        float cI = __fadd_rn(cc[i], bb);
        float m = __fadd_rn(__fmul_rn(b2c, m2), cI);
        if (s2) m = __fsub_rn(m, 1.0f);
        s2 = (m > 1.0f);
        m2 = m;
        cnt += s2 ? 1 : 0;
      }
    }
    float mean = valid ? ((float)cnt / 100.0f) : -1e30f;
    float mx = mean;
#pragma unroll
    for (int i = 8; i >= 1; i >>= 1) mx = fmaxf(mx, __shfl_xor(mx, i, 16));
    float e = valid ? expf(mean - mx) : 0.0f;
    float s = e;
#pragma unroll
    for (int i = 8; i >= 1; i >>= 1) s = __fadd_rn(s, __shfl_xor(s, i, 16));
    if (valid) out[(size_t)b * D_O + o] = e / s;
  }
}

// ---------------------------------------------------------------------------
// Fallback fused temporal kernel (round-3 verbatim) for small ws_size.
// ---------------------------------------------------------------------------
__global__ __launch_bounds__(512) void k_snn(const float* __restrict__ cur1,
                                             const u32* __restrict__ Phi,
                                             const u32* __restrict__ Plo,
                                             const float* __restrict__ b2,
                                             const float* __restrict__ beta1p,
                                             const float* __restrict__ beta2p,
                                             float* __restrict__ out) {
  __shared__ __align__(16) u32 bits[112][66];
  __shared__ float c2[112][18];
  const int b = blockIdx.x;
  const int tid = threadIdx.x;
  const int wave = tid >> 6, lane = tid & 63;
  const float b1c = fminf(fmaxf(beta1p[0], 0.0f), 1.0f);
  const float b2c = fminf(fmaxf(beta2p[0], 0.0f), 1.0f);
  for (int idx = tid; idx < 12 * 66; idx += 512) bits[100 + idx / 66][idx % 66] = 0;
  float cv[4], memv[4];
  bool sp[4];
#pragma unroll
  for (int j = 0; j < 4; ++j) {
    cv[j] = cur1[(size_t)b * D_H + j * 512 + tid];
    memv[j] = 0.0f; sp[j] = false;
  }
  for (int t = 0; t < T_STEPS; ++t) {
    u64 msk[4];
#pragma unroll
    for (int j = 0; j < 4; ++j) {
      float m = __fmul_rn(b1c, memv[j]);
      m = __fadd_rn(m, cv[j]);
      if (sp[j]) m = __fsub_rn(m, 1.0f);
      sp[j] = (m > 1.0f);
      memv[j] = m;
      msk[j] = __ballot(sp[j]);
    }
    if (lane == 0) {
      u64* rowp = (u64*)&bits[t][0];
      rowp[0 * 8 + wave] = msk[0];
      rowp[1 * 8 + wave] = msk[1];
      rowp[2 * 8 + wave] = msk[2];
      rowp[3 * 8 + wave] = msk[3];
    }
  }
  __syncthreads();
  if (wave < 7) {
    f32x4 acc = {0.f, 0.f, 0.f, 0.f};
    const int row0 = wave * 16 + (lane & 15);
    const int shift = (lane >> 4) * 8;
    for (int kb = 0; kb < 64; ++kb) {
      const uint4 bh = *(const uint4*)(Phi + (size_t)(kb * 64 + lane) * 4);
      const uint4 bl = *(const uint4*)(Plo + (size_t)(kb * 64 + lane) * 4);
      u32 w0 = bits[row0][kb] >> shift;
      uint4 a0u;
#pragma unroll
      for (int p = 0; p < 4; ++p) {
        u32 v0 = ((w0 >> (2 * p)) & 1u) * 0x3F80u | ((w0 >> (2 * p + 1)) & 1u) * 0x3F800000u;
        ((u32*)&a0u)[p] = v0;
      }
      s16x8 a0  = __builtin_bit_cast(s16x8, a0u);
      s16x8 bhi = __builtin_bit_cast(s16x8, bh);
      s16x8 blo = __builtin_bit_cast(s16x8, bl);
      acc = __builtin_amdgcn_mfma_f32_16x16x32_bf16(a0, bhi, acc, 0, 0, 0);
      acc = __builtin_amdgcn_mfma_f32_16x16x32_bf16(a0, blo, acc, 0, 0, 0);
    }
    const int colw = lane & 15, rbase = (lane >> 4) * 4;
#pragma unroll
    for (int r = 0; r < 4; ++r) c2[wave * 16 + rbase + r][colw] = acc[r];
  }
  __syncthreads();
  if (tid < 16) {
    const int o = tid;
    const bool valid = (o < D_O);
    const float bb = valid ? b2[o] : 0.0f;
    float m2 = 0.0f; bool s2 = false; int cnt = 0;
    for (int t0 = 0; t0 < T_STEPS; t0 += 10) {
      float cc[10];
#pragma unroll
      for (int i = 0; i < 10; ++i) cc[i] = c2[t0 + i][o];
#pragma unroll
      for (int i = 0; i < 10; ++i) {
        float cI = __fadd_rn(cc[i], bb);
        float m = __fadd_rn(__fmul_rn(b2c, m2), cI);
        if (s2) m = __fsub_rn(m, 1.0f);
        s2 = (m > 1.0f);
        m2 = m;
        cnt += s2 ? 1 : 0;
      }
    }
    float mean = valid ? ((float)cnt / 100.0f) : -1e30f;
    float mx = mean;
#pragma unroll
    for (int i = 8; i >= 1; i >>= 1) mx = fmaxf(mx, __shfl_xor(mx, i, 16));
    float e = valid ? expf(mean - mx) : 0.0f;
    float s = e;
#pragma unroll
    for (int i = 8; i >= 1; i >>= 1) s = __fadd_rn(s, __shfl_xor(s, i, 16));
    if (valid) out[(size_t)b * D_O + o] = e / s;
  }
}

// ---------------------------------------------------------------------------
extern "C" void kernel_launch(void* const* d_in, const int* in_sizes, int n_in,
                              void* d_out, int out_size, void* d_ws, size_t ws_size,
                              hipStream_t stream) {
  const float* x     = (const float*)d_in[0];
  const float* W1    = (const float*)d_in[1];
  const float* b1    = (const float*)d_in[2];
  const float* W2    = (const float*)d_in[3];
  const float* b2    = (const float*)d_in[4];
  const float* beta1 = (const float*)d_in[5];
  const float* beta2 = (const float*)d_in[6];
  float* out = (float*)d_out;

  char* ws = (char*)d_ws;
  // layout: [0,64K) Phi | [64K,128K) Plo | [128K,128K+4M) cur1 |
  //         [4.125M, 6.47M) Xs | [6.47M, 15.84M) Ws
  // bits overlays Xs/Ws (dead after k_gemm1): [4,325,376 .. 19,005,440)
  u32*   Phi  = (u32*)ws;
  u32*   Plo  = (u32*)(ws + 65536);
  float* cur1 = (float*)(ws + 131072);
  uint4* Xs   = (uint4*)(ws + 4325376);
  uint4* Ws_  = (uint4*)(ws + 6782976);               // ends 16,613,376
  u32*   bits = (u32*)(ws + 4325376);                 // 14,680,064 B -> ends 19,005,440
  const bool big = (ws_size >= 19005440u);

  hipLaunchKernelGGL(k_prep, dim3(1016), dim3(256), 0, stream, x, W1, W2, Xs, Ws_, Phi, Plo);
  hipLaunchKernelGGL(k_gemm1, dim3(256), dim3(512), 0, stream, Xs, Ws_, b1, cur1);
  if (big) {
    hipLaunchKernelGGL(k2a, dim3(512), dim3(512), 0, stream, cur1, beta1, bits);
    hipLaunchKernelGGL(k2bc, dim3(512), dim3(512), 0, stream, bits, Phi, Plo, b2, beta2, out);
  } else {
    hipLaunchKernelGGL(k_snn, dim3(512), dim3(512), 0, stream,
                       cur1, Phi, Plo, b2, beta1, beta2, out);
  }
}

// Round 7
// 90.009 us; speedup vs baseline: 1.0516x; 1.0516x over previous
//
#include <hip/hip_runtime.h>
#include <cstdint>

typedef unsigned int u32;
typedef unsigned short u16;
typedef unsigned long long u64;
typedef __attribute__((ext_vector_type(4))) float f32x4;
typedef __attribute__((ext_vector_type(8))) short s16x8;

#define D_IN   784
#define D_H    2048
#define D_O    10
#define T_STEPS 100
#define KB1    25          // ceil(784/32) k-blocks for layer-1 GEMM

static __device__ __forceinline__ u16 f2bf_rn(float f) {
  u32 u = __float_as_uint(f);
  u32 r = u + 0x7FFFu + ((u >> 16) & 1u);
  return (u16)(r >> 16);
}
static __device__ __forceinline__ float bf2f(u16 h) {
  return __uint_as_float(((u32)h) << 16);
}

// ---------------------------------------------------------------------------
// K0a: W2 (f32) -> bf16 hi/lo MFMA B-fragments (round-1/3 verbatim, verified).
// ---------------------------------------------------------------------------
__global__ __launch_bounds__(256) void k_prep_w2(const float* __restrict__ W2,
                                                 u32* __restrict__ Phi,
                                                 u32* __restrict__ Plo) {
  int t = blockIdx.x * 256 + threadIdx.x;
  if (t >= 64 * 64) return;
  int kb = t >> 6, l = t & 63;
  int o = l & 15;
  int kbase = kb * 32 + ((l >> 4) << 3);
  u32 hw[4], lw[4];
#pragma unroll
  for (int p = 0; p < 4; ++p) {
    u32 hp = 0, lp = 0;
#pragma unroll
    for (int q = 0; q < 2; ++q) {
      float f = (o < D_O) ? W2[o * D_H + kbase + 2 * p + q] : 0.0f;
      u16 h = f2bf_rn(f);
      float rr = __fsub_rn(f, bf2f(h));
      u16 lo = f2bf_rn(rr);
      hp |= ((u32)h) << (16 * q);
      lp |= ((u32)lo) << (16 * q);
    }
    hw[p] = hp; lw[p] = lp;
  }
  int base = (kb * 64 + l) * 4;
#pragma unroll
  for (int p = 0; p < 4; ++p) { Phi[base + p] = hw[p]; Plo[base + p] = lw[p]; }
}

// ---------------------------------------------------------------------------
// K0b: triple-split x and W1 into bf16 MFMA fragments (round-3 verbatim).
// ---------------------------------------------------------------------------
__global__ __launch_bounds__(256) void k_split(const float* __restrict__ x,
                                               const float* __restrict__ W1,
                                               uint4* __restrict__ Xs,
                                               uint4* __restrict__ Ws) {
  int t = blockIdx.x * 256 + threadIdx.x;
  const int XT = KB1 * 32 * 64;     // 51200
  const int WT = KB1 * 128 * 64;    // 204800
  if (t >= XT + WT) return;
  const float* base; uint4* dst; int kb, l, frag, nfr;
  if (t < XT) {
    l = t & 63; int f = t >> 6; frag = f & 31; kb = f >> 5;
    base = x; dst = Xs; nfr = 32;
  } else {
    int t2 = t - XT;
    l = t2 & 63; int f = t2 >> 6; frag = f & 127; kb = f >> 7;
    base = W1; dst = Ws; nfr = 128;
  }
  int row = frag * 16 + (l & 15);
  int ks = kb * 32 + ((l >> 4) << 3);
  const float* rp = base + (size_t)row * D_IN;
  float e[8];
#pragma unroll
  for (int q = 0; q < 8; ++q) e[q] = (ks + q < D_IN) ? rp[ks + q] : 0.0f;
  u32 w0[4], w1[4], w2[4];
#pragma unroll
  for (int p = 0; p < 4; ++p) {
    u32 a0 = 0, a1 = 0, a2 = 0;
#pragma unroll
    for (int q = 0; q < 2; ++q) {
      float v = e[2 * p + q];
      u16 s0 = f2bf_rn(v); float r1 = __fsub_rn(v, bf2f(s0));
      u16 s1 = f2bf_rn(r1); float r2 = __fsub_rn(r1, bf2f(s1));
      u16 s2 = f2bf_rn(r2);
      a0 |= ((u32)s0) << (16 * q);
      a1 |= ((u32)s1) << (16 * q);
      a2 |= ((u32)s2) << (16 * q);
    }
    w0[p] = a0; w1[p] = a1; w2[p] = a2;
  }
  size_t bi = ((size_t)kb * nfr + frag) * 64 + l;
  size_t ss = (size_t)KB1 * nfr * 64;
  dst[0 * ss + bi] = make_uint4(w0[0], w0[1], w0[2], w0[3]);
  dst[1 * ss + bi] = make_uint4(w1[0], w1[1], w1[2], w1[3]);
  dst[2 * ss + bi] = make_uint4(w2[0], w2[1], w2[2], w2[3]);
}

// ---------------------------------------------------------------------------
// K1: cur1 = x @ W1^T + b1 via 6-product bf16-triple MFMA (round-3 verbatim).
// ---------------------------------------------------------------------------
__global__ __launch_bounds__(512) void k_gemm1(const uint4* __restrict__ Xs,
                                               const uint4* __restrict__ Ws,
                                               const float* __restrict__ b1,
                                               float* __restrict__ cur1) {
  __shared__ float4 comb[16][64];   // 16 KB
  const int tid = threadIdx.x, wave = tid >> 6, lane = tid & 63;
  const int mb = blockIdx.y, nb = blockIdx.x;
  const int wn = wave & 3;
  const int nfrag = nb * 4 + wn;
  const size_t ssx = (size_t)KB1 * 32 * 64;
  const size_t ssw = (size_t)KB1 * 128 * 64;
  f32x4 acc[4] = {{0.f,0.f,0.f,0.f},{0.f,0.f,0.f,0.f},{0.f,0.f,0.f,0.f},{0.f,0.f,0.f,0.f}};
  for (int kb = (wave >> 2); kb < KB1; kb += 2) {
    const size_t bb = (size_t)kb * 8192 + (size_t)nfrag * 64 + lane;
    uint4 b0u = Ws[0 * ssw + bb];
    uint4 b1u = Ws[1 * ssw + bb];
    uint4 b2u = Ws[2 * ssw + bb];
    s16x8 B0 = __builtin_bit_cast(s16x8, b0u);
    s16x8 B1 = __builtin_bit_cast(s16x8, b1u);
    s16x8 B2 = __builtin_bit_cast(s16x8, b2u);
#pragma unroll
    for (int fm = 0; fm < 4; ++fm) {
      const size_t ab = (size_t)kb * 2048 + (size_t)(mb * 4 + fm) * 64 + lane;
      uint4 a0u = Xs[0 * ssx + ab];
      uint4 a1u = Xs[1 * ssx + ab];
      uint4 a2u = Xs[2 * ssx + ab];
      s16x8 A0 = __builtin_bit_cast(s16x8, a0u);
      s16x8 A1 = __builtin_bit_cast(s16x8, a1u);
      s16x8 A2 = __builtin_bit_cast(s16x8, a2u);
      acc[fm] = __builtin_amdgcn_mfma_f32_16x16x32_bf16(A0, B0, acc[fm], 0, 0, 0);
      acc[fm] = __builtin_amdgcn_mfma_f32_16x16x32_bf16(A0, B1, acc[fm], 0, 0, 0);
      acc[fm] = __builtin_amdgcn_mfma_f32_16x16x32_bf16(A1, B0, acc[fm], 0, 0, 0);
      acc[fm] = __builtin_amdgcn_mfma_f32_16x16x32_bf16(A1, B1, acc[fm], 0, 0, 0);
      acc[fm] = __builtin_amdgcn_mfma_f32_16x16x32_bf16(A0, B2, acc[fm], 0, 0, 0);
      acc[fm] = __builtin_amdgcn_mfma_f32_16x16x32_bf16(A2, B0, acc[fm], 0, 0, 0);
    }
  }
  if (wave >= 4) {
#pragma unroll
    for (int fm = 0; fm < 4; ++fm)
      comb[wn * 4 + fm][lane] = make_float4(acc[fm][0], acc[fm][1], acc[fm][2], acc[fm][3]);
  }
  __syncthreads();
  if (wave < 4) {
    const float bv = b1[nfrag * 16 + (lane & 15)];
    const int rbase = (lane >> 4) * 4, col = lane & 15;
#pragma unroll
    for (int fm = 0; fm < 4; ++fm) {
      float4 o = comb[wn * 4 + fm][lane];
      float v[4] = {acc[fm][0] + o.x, acc[fm][1] + o.y, acc[fm][2] + o.z, acc[fm][3] + o.w};
#pragma unroll
      for (int r = 0; r < 4; ++r) {
        int m = mb * 64 + fm * 16 + rbase + r;
        cur1[(size_t)m * D_H + nfrag * 16 + col] = v[r] + bv;
      }
    }
  }
}

// ---------------------------------------------------------------------------
// K2: NEW fused temporal kernel. One block (512 thr) per batch row.
//  B: register-accumulated recurrence (lane t captures step-t ballot via
//     cndmask), bulk-dumped twice into LDS bit-matrix bitsS[h32][t].
//  C: cur2 via MFMA with Phi/Plo LDS-chunk staging (8 chunks of 8 kb).
//  D: layer-2 recurrence + mean + softmax (batched c2 reads).
// ---------------------------------------------------------------------------
__global__ __launch_bounds__(512) void k_snn2(const float* __restrict__ cur1,
                                              const u32* __restrict__ Phi,
                                              const u32* __restrict__ Plo,
                                              const float* __restrict__ b2,
                                              const float* __restrict__ beta1p,
                                              const float* __restrict__ beta2p,
                                              float* __restrict__ out) {
  __shared__ u32  bitsS[64][112];   // [h32][t], 28 KB
  __shared__ uint4 PhiS[8][64];     // 8 KB
  __shared__ uint4 PloS[8][64];     // 8 KB
  __shared__ float c2[112][18];     // 8 KB
  const int b = blockIdx.x, tid = threadIdx.x;
  const int wave = tid >> 6, lane = tid & 63;
  const float b1c = fminf(fmaxf(beta1p[0], 0.0f), 1.0f);
  const float b2c = fminf(fmaxf(beta2p[0], 0.0f), 1.0f);

  // ---- phase B: layer-1 recurrence, exact numpy op order ----
  float cv[4], memv[4]; bool sp[4];
  u32 alo[4], ahi[4];
#pragma unroll
  for (int j = 0; j < 4; ++j) {
    cv[j] = cur1[(size_t)b * D_H + j * 512 + tid];
    memv[j] = 0.0f; sp[j] = false; alo[j] = 0u; ahi[j] = 0u;
  }
  for (int t = 0; t < 64; ++t) {
    const bool mine = (lane == t);
#pragma unroll
    for (int j = 0; j < 4; ++j) {
      float m = __fmul_rn(b1c, memv[j]);
      m = __fadd_rn(m, cv[j]);
      if (sp[j]) m = __fsub_rn(m, 1.0f);
      sp[j] = (m > 1.0f);
      memv[j] = m;
      u64 msk = __ballot(sp[j]);
      alo[j] = mine ? (u32)msk : alo[j];
      ahi[j] = mine ? (u32)(msk >> 32) : ahi[j];
    }
  }
#pragma unroll
  for (int j = 0; j < 4; ++j) {
    bitsS[j * 16 + wave * 2 + 0][lane] = alo[j];
    bitsS[j * 16 + wave * 2 + 1][lane] = ahi[j];
    alo[j] = 0u; ahi[j] = 0u;
  }
  for (int t = 64; t < T_STEPS; ++t) {
    const bool mine = (lane == t - 64);
#pragma unroll
    for (int j = 0; j < 4; ++j) {
      float m = __fmul_rn(b1c, memv[j]);
      m = __fadd_rn(m, cv[j]);
      if (sp[j]) m = __fsub_rn(m, 1.0f);
      sp[j] = (m > 1.0f);
      memv[j] = m;
      u64 msk = __ballot(sp[j]);
      alo[j] = mine ? (u32)msk : alo[j];
      ahi[j] = mine ? (u32)(msk >> 32) : ahi[j];
    }
  }
  if (lane < 48) {   // t = 64..111; lanes 36..47 carry zeros (pad rows)
#pragma unroll
    for (int j = 0; j < 4; ++j) {
      bitsS[j * 16 + wave * 2 + 0][64 + lane] = alo[j];
      bitsS[j * 16 + wave * 2 + 1][64 + lane] = ahi[j];
    }
  }
  __syncthreads();

  // ---- phase C: cur2 via MFMA, Phi/Plo staged in 8-kb chunks ----
  f32x4 acc = {0.f, 0.f, 0.f, 0.f};
  const int trow = wave * 16 + (lane & 15);
  const int shift = (lane >> 4) * 8;
  for (int c = 0; c < 8; ++c) {
    PhiS[wave][lane] = *(const uint4*)(Phi + (size_t)((c * 8 + wave) * 64 + lane) * 4);
    PloS[wave][lane] = *(const uint4*)(Plo + (size_t)((c * 8 + wave) * 64 + lane) * 4);
    __syncthreads();
    if (wave < 7) {
#pragma unroll
      for (int kk = 0; kk < 8; ++kk) {
        u32 w8 = (bitsS[c * 8 + kk][trow] >> shift) & 0xFFu;
        u32 u = w8 | (w8 << 15);
        uint4 a0u;
        ((u32*)&a0u)[0] = ( u        & 0x00010001u) * 0x3F80u;
        ((u32*)&a0u)[1] = ((u >> 2)  & 0x00010001u) * 0x3F80u;
        ((u32*)&a0u)[2] = ((u >> 4)  & 0x00010001u) * 0x3F80u;
        ((u32*)&a0u)[3] = ((u >> 6)  & 0x00010001u) * 0x3F80u;
        s16x8 a   = __builtin_bit_cast(s16x8, a0u);
        s16x8 bhi = __builtin_bit_cast(s16x8, PhiS[kk][lane]);
        s16x8 blo = __builtin_bit_cast(s16x8, PloS[kk][lane]);
        acc = __builtin_amdgcn_mfma_f32_16x16x32_bf16(a, bhi, acc, 0, 0, 0);
        acc = __builtin_amdgcn_mfma_f32_16x16x32_bf16(a, blo, acc, 0, 0, 0);
      }
    }
    __syncthreads();   // protect next chunk's staging stores
  }
  if (wave < 7) {
    const int colw = lane & 15, rbase = (lane >> 4) * 4;
#pragma unroll
    for (int r = 0; r < 4; ++r) c2[wave * 16 + rbase + r][colw] = acc[r];
  }
  __syncthreads();

  // ---- phase D: layer-2 recurrence + mean + softmax ----
  if (tid < 16) {
    const int o = tid;
    const bool valid = (o < D_O);
    const float bb = valid ? b2[o] : 0.0f;
    float m2 = 0.0f; bool s2 = false; int cnt = 0;
    for (int t0 = 0; t0 < T_STEPS; t0 += 10) {
      float cc[10];
#pragma unroll
      for (int i = 0; i < 10; ++i) cc[i] = c2[t0 + i][o];
#pragma unroll
      for (int i = 0; i < 10; ++i) {
        float cI = __fadd_rn(cc[i], bb);
        float m = __fadd_rn(__fmul_rn(b2c, m2), cI);
        if (s2) m = __fsub_rn(m, 1.0f);
        s2 = (m > 1.0f);
        m2 = m;
        cnt += s2 ? 1 : 0;
      }
    }
    float mean = valid ? ((float)cnt / 100.0f) : -1e30f;
    float mx = mean;
#pragma unroll
    for (int i = 8; i >= 1; i >>= 1) mx = fmaxf(mx, __shfl_xor(mx, i, 16));
    float e = valid ? expf(mean - mx) : 0.0f;
    float s = e;
#pragma unroll
    for (int i = 8; i >= 1; i >>= 1) s = __fadd_rn(s, __shfl_xor(s, i, 16));
    if (valid) out[(size_t)b * D_O + o] = e / s;
  }
}

// ---------------------------------------------------------------------------
extern "C" void kernel_launch(void* const* d_in, const int* in_sizes, int n_in,
                              void* d_out, int out_size, void* d_ws, size_t ws_size,
                              hipStream_t stream) {
  const float* x     = (const float*)d_in[0];
  const float* W1    = (const float*)d_in[1];
  const float* b1    = (const float*)d_in[2];
  const float* W2    = (const float*)d_in[3];
  const float* b2    = (const float*)d_in[4];
  const float* beta1 = (const float*)d_in[5];
  const float* beta2 = (const float*)d_in[6];
  float* out = (float*)d_out;

  char* ws = (char*)d_ws;
  float* cur1 = (float*)ws;                           // 4,194,304 B
  u32*   Phi  = (u32*)(ws + 4194304);                 // 65,536 B
  u32*   Plo  = (u32*)(ws + 4194304 + 65536);         // 65,536 B
  uint4* Xs   = (uint4*)(ws + 4325376);               // 2,457,600 B
  uint4* Ws_  = (uint4*)(ws + 6782976);               // 9,830,400 B

  hipLaunchKernelGGL(k_prep_w2, dim3(16), dim3(256), 0, stream, W2, Phi, Plo);
  hipLaunchKernelGGL(k_split, dim3(1000), dim3(256), 0, stream, x, W1, Xs, Ws_);
  hipLaunchKernelGGL(k_gemm1, dim3(32, 8), dim3(512), 0, stream, Xs, Ws_, b1, cur1);
  hipLaunchKernelGGL(k_snn2, dim3(512), dim3(512), 0, stream,
                     cur1, Phi, Plo, b2, beta1, beta2, out);
}